// Round 10
// baseline (233.758 us; speedup 1.0000x reference)
//
#include <hip/hip_runtime.h>

#define S_SEQ 256
#define N_RES 512
#define CCH   32

typedef __attribute__((ext_vector_type(8))) short bf16x8;
typedef __attribute__((ext_vector_type(4))) float f32x4;
typedef __attribute__((ext_vector_type(2))) unsigned int u32x2;

__device__ __forceinline__ unsigned short f2bf(float x) {
    unsigned int u = __float_as_uint(x);
    return (unsigned short)((u + 0x7FFFu + ((u >> 16) & 1u)) >> 16);
}

__device__ __forceinline__ unsigned int cvtpk(float lo, float hi) {
    unsigned int r;
    asm("v_cvt_pk_bf16_f32 %0, %1, %2" : "=v"(r) : "v"(lo), "v"(hi));
    return r;
}

#define GLOAD_LDS16(gp, lp) __builtin_amdgcn_global_load_lds( \
    (const __attribute__((address_space(1))) unsigned int*)(gp), \
    (__attribute__((address_space(3))) unsigned int*)(lp), 16, 0, 0)

#define BAR()    do { __builtin_amdgcn_s_barrier(); asm volatile("" ::: "memory"); } while (0)
#define WLGKM0() asm volatile("s_waitcnt lgkmcnt(0)" ::: "memory")
#define WVM(n)   asm volatile("s_waitcnt vmcnt(" #n ")" ::: "memory")

// ---------------------------------------------------------------------------
// Kernel 1: LayerNorm + dual projection + mask. A and B both written as the
// dual-row 128B image over 256-row tiles (r5/r6-verified):
//   row = n*32+c; tile = row>>8; half = (row>>7)&1; ir = row&127
//   byte = tile*131072 + kt*16384 + ir*128 + ((((half<<2)|q) ^ (ir&7))<<4)
// ---------------------------------------------------------------------------
__global__ __launch_bounds__(256) void prep_ab(
    const float* __restrict__ m, const float* __restrict__ mask,
    const float* __restrict__ gam, const float* __restrict__ bet,
    const float* __restrict__ Wa, const float* __restrict__ ba,
    const float* __restrict__ Wb, const float* __restrict__ bb,
    char* __restrict__ Ag, char* __restrict__ Bg)
{
    __shared__ float WaL[1024], WbL[1024];
    __shared__ float gL[32], btL[32], baL[32], bbL[32];
    __shared__ unsigned short At[32 * 256];
    __shared__ unsigned short Bt[32 * 256];

    const int n = blockIdx.x;
    const int t = threadIdx.x;

    for (int i = t; i < 1024; i += 256) { WaL[i] = Wa[i]; WbL[i] = Wb[i]; }
    if (t < 32) { gL[t] = gam[t]; btL[t] = bet[t]; baL[t] = ba[t]; bbL[t] = bb[t]; }
    __syncthreads();

    const int s = t;
    float mv[32];
    const float* mrow = m + ((size_t)s * N_RES + n) * CCH;
#pragma unroll
    for (int c4 = 0; c4 < 8; c4++) {
        f32x4 v = *(const f32x4*)(mrow + c4 * 4);
        mv[c4 * 4 + 0] = v.x; mv[c4 * 4 + 1] = v.y;
        mv[c4 * 4 + 2] = v.z; mv[c4 * 4 + 3] = v.w;
    }
    float mu = 0.f;
#pragma unroll
    for (int c = 0; c < 32; c++) mu += mv[c];
    mu *= (1.f / 32.f);
    float var = 0.f;
#pragma unroll
    for (int c = 0; c < 32; c++) { float d = mv[c] - mu; var += d * d; }
    var *= (1.f / 32.f);
    float rs = rsqrtf(var + 1e-5f);
    float mh[32];
#pragma unroll
    for (int c = 0; c < 32; c++) mh[c] = (mv[c] - mu) * rs * gL[c] + btL[c];

    const float msk = mask[(size_t)s * N_RES + n];

    f32x4 av[8], bv[8];
#pragma unroll
    for (int cg = 0; cg < 8; cg++) { av[cg] = (f32x4)0.f; bv[cg] = (f32x4)0.f; }
#pragma unroll
    for (int k = 0; k < 32; k++) {
        float x = mh[k];
#pragma unroll
        for (int cg = 0; cg < 8; cg++) {
            f32x4 wa4 = *(const f32x4*)&WaL[k * 32 + cg * 4];
            f32x4 wb4 = *(const f32x4*)&WbL[k * 32 + cg * 4];
            av[cg] += x * wa4;
            bv[cg] += x * wb4;
        }
    }
#pragma unroll
    for (int cg = 0; cg < 8; cg++) {
#pragma unroll
        for (int u = 0; u < 4; u++) {
            int c = cg * 4 + u;
            At[c * 256 + s] = f2bf((av[cg][u] + baL[c]) * msk);
            Bt[c * 256 + s] = f2bf((bv[cg][u] + bbL[c]) * msk);
        }
    }
    __syncthreads();

    // flush (16B chunks): row = n*32+c, 256-row tiles
    const size_t tbase = (size_t)(n >> 3) * 131072;
    const int half = (n >> 2) & 1;                 // (row>>7)&1
    const int irbase = (n & 3) * 32;               // row&127 base
#pragma unroll
    for (int u = 0; u < 4; u++) {
        int cid = t * 4 + u;             // 1024 chunks: c (32) x 8-seq group g (32)
        int c = cid >> 5, g = cid & 31;
        int kt = g >> 2, q = g & 3;      // s = kt*32 + q*8 + j
        int slot = ((half << 2) | q) ^ (c & 7);    // ir&7 == c&7
        size_t off = tbase + (size_t)kt * 16384 + (size_t)(irbase + c) * 128 + (slot << 4);
        *(uint4*)(Ag + off) = *(const uint4*)(At + c * 256 + g * 8);
        *(uint4*)(Bg + off) = *(const uint4*)(Bt + c * 256 + g * 8);
    }
}

// ---------------------------------------------------------------------------
// Kernel 2: Wt3[e][ch][c] = bf16(Wout[(c*32+e)][ch])   (32 x 32 x 32 bf16)
// ---------------------------------------------------------------------------
__global__ __launch_bounds__(256) void kwt(const float* __restrict__ Wout,
                                           unsigned short* __restrict__ Wt3)
{
    int idx = blockIdx.x * 256 + threadIdx.x;   // 32768
    int e = idx >> 10, ch = (idx >> 5) & 31, c = idx & 31;
    Wt3[idx] = f2bf(Wout[(size_t)(c * 32 + e) * 32 + ch]);
}

// ---------------------------------------------------------------------------
// Kernel 3: inv_norm[i][j] = 1 / (sum_s mask[s,i]*mask[s,j] + 1e-3)
// ---------------------------------------------------------------------------
__global__ __launch_bounds__(256) void knorm(const float* __restrict__ mask,
                                             float* __restrict__ inv_norm)
{
    __shared__ float Mi[64][65];
    __shared__ float Mj[64][65];
    const int bi = blockIdx.x >> 3, bj = blockIdx.x & 7;
    const int t = threadIdx.x;
    const int ty = t >> 4, tx = t & 15;

    float acc[4][4];
#pragma unroll
    for (int a = 0; a < 4; a++)
#pragma unroll
        for (int b = 0; b < 4; b++) acc[a][b] = 0.f;

    for (int sc = 0; sc < 4; sc++) {
        for (int e = t; e < 4096; e += 256) {
            int sr = e >> 6, col = e & 63;
            Mi[sr][col] = mask[(size_t)(sc * 64 + sr) * N_RES + bi * 64 + col];
            Mj[sr][col] = mask[(size_t)(sc * 64 + sr) * N_RES + bj * 64 + col];
        }
        __syncthreads();
        for (int sp = 0; sp < 64; sp++) {
#pragma unroll
            for (int a = 0; a < 4; a++)
#pragma unroll
                for (int b = 0; b < 4; b++)
                    acc[a][b] += Mi[sp][ty * 4 + a] * Mj[sp][tx * 4 + b];
        }
        __syncthreads();
    }
#pragma unroll
    for (int a = 0; a < 4; a++)
#pragma unroll
        for (int b = 0; b < 4; b++) {
            int i = bi * 64 + ty * 4 + a;
            int j = bj * 64 + tx * 4 + b;
            inv_norm[(size_t)i * N_RES + j] = 1.f / (acc[a][b] + 1e-3f);
        }
}

// ---------------------------------------------------------------------------
// Kernel 10: 256x256 tile, 8 waves x (128x64), BK=32, dbuf 2x32KB, LDS 66KB
// -> 2 blocks/CU, 16 waves (regs: 128 AGPR acc + ~116 VGPR <= 256).
// LDS frag traffic 375 B/MFMA (vs 512 at 64x64 wave tiles). Counted
// vmcnt(4) schedule. Epilogue: 2 rounds x 32 pairs, cvt_pk bf16 dump,
// conflict-free G layout (f(e)=(e>>1)&3), K split 4 ways, ps reduce.
// ---------------------------------------------------------------------------
__global__ __launch_bounds__(512, 2) void kmain10(
    const char* __restrict__ Ag, const char* __restrict__ Bg,
    const unsigned short* __restrict__ Wt3, const float* __restrict__ inv_norm,
    const float* __restrict__ bout, float* __restrict__ out)
{
    __shared__ __align__(16) char sm[66048];   // dbuf [0,65536); epi G [0,66048)

    const int bid = blockIdx.x;                // 4096 = 64 TI x 64 TJ
    const int xcd = bid & 7;
    const int xidx = bid >> 3;                 // 0..511
    const int TI = xcd * 8 + ((xidx >> 4) & 7);
    const int TJ = (xidx >> 7) * 16 + (xidx & 15);

    const int t = threadIdx.x;
    const int lane = t & 63, wid = t >> 6;
    const int wr = wid >> 2, wc = wid & 3;     // wave tile 128x64
    const int rl = lane & 15, h4 = lane >> 4;

    const char* pa = Ag + (size_t)TI * 131072;
    const char* pb = Bg + (size_t)TJ * 131072;

#define SH(kt) do { \
    char* db_ = sm + (((kt) & 1) * 32768); \
    GLOAD_LDS16(pa + (kt) * 16384 + t * 16,        db_ + t * 16); \
    GLOAD_LDS16(pa + (kt) * 16384 + 8192 + t * 16, db_ + 8192 + t * 16); \
    GLOAD_LDS16(pb + (kt) * 16384 + t * 16,        db_ + 16384 + t * 16); \
    GLOAD_LDS16(pb + (kt) * 16384 + 8192 + t * 16, db_ + 24576 + t * 16); \
} while (0)

    // lane-constant frag offsets (256-row dual-row image)
    const int abase = rl * 128 + ((((wr << 2) | h4) ^ (rl & 7)) << 4);       // + am*2048
    const int bbase = 16384 + ((wc & 1) * 64 + rl) * 128
                    + (((((wc >> 1) << 2) | h4) ^ (rl & 7)) << 4);           // + bn*2048

    f32x4 acc[8][4];
#pragma unroll
    for (int a = 0; a < 8; a++)
#pragma unroll
        for (int b = 0; b < 4; b++) acc[a][b] = (f32x4)0.f;

    SH(0);
    SH(1);

#pragma unroll
    for (int kt = 0; kt < 8; kt++) {
        if (kt < 7) { WVM(4); } else { WVM(0); }
        BAR();                                 // kt's data visible to all waves
        const char* buf = sm + ((kt & 1) * 32768);
        bf16x8 af[8], bfr[4];
#pragma unroll
        for (int am = 0; am < 8; am++)
            af[am] = *(const bf16x8*)(buf + abase + am * 2048);
#pragma unroll
        for (int bn = 0; bn < 4; bn++)
            bfr[bn] = *(const bf16x8*)(buf + bbase + bn * 2048);
        __builtin_amdgcn_s_setprio(1);
#pragma unroll
        for (int am = 0; am < 8; am++)
#pragma unroll
            for (int bn = 0; bn < 4; bn++)
                acc[am][bn] = __builtin_amdgcn_mfma_f32_16x16x32_bf16(
                    af[am], bfr[bn], acc[am][bn], 0, 0, 0);
        __builtin_amdgcn_s_setprio(0);
        BAR();                                 // all waves' frags consumed
        if (kt <= 5) SH(kt + 2);               // overwrites kt's buffer (safe)
    }
#undef SH

    // ================= epilogue: 2 rounds of 32 pairs ======================
    float* ps = (float*)sm;                    // [8][16][34] f32 overlays G head
#pragma unroll
    for (int R = 0; R < 2; R++) {
        // ---- G dump: am = R*4 + a; cvt_pk bf16; conflict-light layout ----
#pragma unroll
        for (int a = 0; a < 4; a++) {
            const int am = R * 4 + a;
            const int lpr = (wr * 2 + (a >> 1)) * 8 + wc * 2;
            const int cs = ((a & 1) << 1) + (h4 >> 1);
#pragma unroll
            for (int bn = 0; bn < 4; bn++) {
                const int lp = lpr + (bn >> 1);
                const int e = ((bn & 1) << 4) + rl;
                u32x2 wv;
                wv[0] = cvtpk(acc[am][bn][0], acc[am][bn][1]);
                wv[1] = cvtpk(acc[am][bn][2], acc[am][bn][3]);
                *(u32x2*)(sm + lp * 2064 + e * 64 +
                          ((cs ^ ((e >> 1) & 3)) << 4) + ((h4 & 1) << 3)) = wv;
            }
        }
        WLGKM0();
        BAR();
        // ---- second GEMM: slot = wid>>2 (16 pairs), K quarter = wid&3 ----
        const int slotR = wid >> 2, kq = wid & 3;
        f32x4 ae0 = (f32x4)0.f, ae1 = (f32x4)0.f;
        const char* grow = sm + (slotR * 16 + rl) * 2064;
#pragma unroll
        for (int es = 0; es < 8; es++) {
            const int e = kq * 8 + es;
            bf16x8 ga = *(const bf16x8*)(grow + e * 64 + ((h4 ^ ((e >> 1) & 3)) << 4));
            bf16x8 wb0 = *(const bf16x8*)(Wt3 + (size_t)e * 1024 + rl * 32 + h4 * 8);
            bf16x8 wb1 = *(const bf16x8*)(Wt3 + (size_t)e * 1024 + (16 + rl) * 32 + h4 * 8);
            ae0 = __builtin_amdgcn_mfma_f32_16x16x32_bf16(ga, wb0, ae0, 0, 0, 0);
            ae1 = __builtin_amdgcn_mfma_f32_16x16x32_bf16(ga, wb1, ae1, 0, 0, 0);
        }
        BAR();                                 // ga consumed -> G head reusable
        // ---- partials ps[(slot*4+kq)][pair16=h4*4+r][ch] (stride 34) ----
#pragma unroll
        for (int r = 0; r < 4; r++) {
            ps[((slotR * 4 + kq) * 16 + h4 * 4 + r) * 34 + rl]      = ae0[r];
            ps[((slotR * 4 + kq) * 16 + h4 * 4 + r) * 34 + 16 + rl] = ae1[r];
        }
        WLGKM0();
        BAR();
        // ---- reduce 4 K-quarters + bias + mask-norm + coalesced store ----
#pragma unroll
        for (int u = 0; u < 2; u++) {
            const int idx = u * 512 + t;
            const int lp = idx >> 5, ch = idx & 31;
            float v = 0.f;
#pragma unroll
            for (int k2 = 0; k2 < 4; k2++)
                v += ps[(((lp >> 4) * 4 + k2) * 16 + (lp & 15)) * 34 + ch];
            const int lr = lp >> 3;
            const int pi = (lr >> 1) * 4 + 2 * R + (lr & 1);
            const int pj = lp & 7;
            const int i = TI * 8 + pi, j = TJ * 8 + pj;
            out[((size_t)(i * N_RES + j)) * CCH + ch] =
                (v + bout[ch]) * inv_norm[(size_t)i * N_RES + j];
        }
        BAR();                                 // reduce done -> G reusable (R=1)
    }
}

// ---------------------------------------------------------------------------
extern "C" void kernel_launch(void* const* d_in, const int* in_sizes, int n_in,
                              void* d_out, int out_size, void* d_ws, size_t ws_size,
                              hipStream_t stream)
{
    const float* m    = (const float*)d_in[0];
    const float* mask = (const float*)d_in[1];
    const float* gam  = (const float*)d_in[2];
    const float* bet  = (const float*)d_in[3];
    const float* Wa   = (const float*)d_in[4];
    const float* ba   = (const float*)d_in[5];
    const float* Wb   = (const float*)d_in[6];
    const float* bb   = (const float*)d_in[7];
    const float* Wout = (const float*)d_in[8];
    const float* bout = (const float*)d_in[9];
    float* out = (float*)d_out;

    char* ws = (char*)d_ws;
    char* Ag = ws;                                            //  8,388,608 B
    char* Bg = ws + 8388608;                                  //  8,388,608 B
    unsigned short* Wt3 = (unsigned short*)(ws + 16777216);   //     65,536 B
    float* inv_norm = (float*)(ws + 16842752);                //  1,048,576 B

    prep_ab<<<dim3(N_RES), dim3(256), 0, stream>>>(m, mask, gam, bet, Wa, ba, Wb, bb, Ag, Bg);
    kwt<<<dim3(128), dim3(256), 0, stream>>>(Wout, Wt3);
    knorm<<<dim3(64), dim3(256), 0, stream>>>(mask, inv_norm);
    kmain10<<<dim3(4096), dim3(512), 0, stream>>>(Ag, Bg, Wt3, inv_norm, bout, out);
}